// Round 2
// baseline (548.821 us; speedup 1.0000x reference)
//
#include <hip/hip_runtime.h>
#include <hip/hip_bf16.h>

#define VOCAB 512
#define EMB   128
#define HID   64
#define BATCH 256
#define TLEN  1024

__device__ __forceinline__ float fast_tanh(float x) {
    // tanh(x) = 1 - 2/(exp(2x)+1); exact at both saturated ends.
    float e = __expf(2.0f * x);
    return 1.0f - 2.0f / (e + 1.0f);
}

// ---------------------------------------------------------------------------
// Kernel 1: P0[v][i] = sum_e emb[v][e]*Wih0[i][e] + bih0[i] + bhh0[i]  (fp32)
// The entire layer-0 input path collapses to a 512x64 lookup table.
// ---------------------------------------------------------------------------
__global__ void __launch_bounds__(64) p0_kernel(
    const float* __restrict__ emb,
    const float* __restrict__ wih0,
    const float* __restrict__ bih0,
    const float* __restrict__ bhh0,
    float* __restrict__ P0)
{
    const int v = blockIdx.x;    // vocab row
    const int i = threadIdx.x;   // hidden index
    const float4* er = (const float4*)(emb  + v * EMB);
    const float4* wr = (const float4*)(wih0 + i * EMB);
    float a0 = 0.f, a1 = 0.f, a2 = 0.f, a3 = 0.f;
    #pragma unroll
    for (int k = 0; k < EMB / 4; ++k) {
        float4 e4 = er[k];
        float4 w4 = wr[k];
        a0 = fmaf(e4.x, w4.x, a0);
        a1 = fmaf(e4.y, w4.y, a1);
        a2 = fmaf(e4.z, w4.z, a2);
        a3 = fmaf(e4.w, w4.w, a3);
    }
    P0[v * HID + i] = (a0 + a1) + (a2 + a3) + bih0[i] + bhh0[i];
}

// ---------------------------------------------------------------------------
// Kernel 2: one block per batch row; 3 waves pipeline the recurrence.
//   wave0 @ iter s: h0[s]   = tanh(P0[x[s]] + Whh0 h0[s-1])
//   wave1 @ iter s: p1[s-1] = Wih1 h0[s-1]
//   wave2 @ iter s: h1[s-2] = tanh(p1[s-2] + Whh1 h1[s-3] + bih1 + bhh1)
// Weights: one matrix row per lane, resident in 64 VGPRs per wave.
// h vectors in LDS; broadcast float4 reads (same addr across lanes) are free.
// ---------------------------------------------------------------------------
__global__ void __launch_bounds__(192, 1) rnn_kernel(
    const int*   __restrict__ xs,
    const float* __restrict__ P0,
    const float* __restrict__ Whh0,
    const float* __restrict__ Wih1,
    const float* __restrict__ Whh1,
    const float* __restrict__ bih1,
    const float* __restrict__ bhh1,
    const float* __restrict__ W1,
    const float* __restrict__ b1,
    const float* __restrict__ W2,
    const float* __restrict__ b2,
    float*       __restrict__ out)
{
    __shared__ float h0ring[2][HID];
    __shared__ float p1ring[2][HID];
    __shared__ float hs1[HID];

    const int b    = blockIdx.x;
    const int tid  = threadIdx.x;
    const int wv   = tid >> 6;    // wave id 0..2
    const int lane = tid & 63;

    if (tid < HID) {
        h0ring[0][tid] = 0.f; h0ring[1][tid] = 0.f;
        p1ring[0][tid] = 0.f; p1ring[1][tid] = 0.f;
        hs1[tid] = 0.f;
    }

    // Per-wave weight row -> registers (fp32)
    const float* wrow =
        (wv == 0) ? (Whh0 + lane * HID) :
        (wv == 1) ? (Wih1 + lane * HID) : (Whh1 + lane * HID);
    float w[HID];
    {
        const float4* wr4 = (const float4*)wrow;
        #pragma unroll
        for (int k = 0; k < HID / 4; ++k) {
            float4 u = wr4[k];
            w[4 * k + 0] = u.x; w[4 * k + 1] = u.y;
            w[4 * k + 2] = u.z; w[4 * k + 3] = u.w;
        }
    }
    float b1s = 0.f;
    if (wv == 2) b1s = bih1[lane] + bhh1[lane];

    const int* xrow = xs + b * TLEN;
    // wave0 prefetch state: a_pre = P0 row for step s; xv_n = x for step s+1
    float a_pre = 0.f;
    int   xv_n  = 0;
    if (wv == 0) {
        a_pre = P0[xrow[0] * HID + lane];
        xv_n  = xrow[1];
    }

    __syncthreads();

    for (int s = 0; s < TLEN + 2; ++s) {
        if (wv == 0) {
            if (s < TLEN) {
                // issue prefetches for s+1 / s+2 early (no dependence on h)
                float a_nxt = P0[xv_n * HID + lane];
                int   x_nxt = xrow[(s + 2 < TLEN) ? (s + 2) : (TLEN - 1)];
                const float4* h4 = (const float4*)h0ring[(s + 1) & 1];
                float ac0 = a_pre, ac1 = 0.f, ac2 = 0.f, ac3 = 0.f;
                #pragma unroll
                for (int k = 0; k < 16; ++k) {
                    float4 hv = h4[k];
                    ac0 = fmaf(hv.x, w[4 * k + 0], ac0);
                    ac1 = fmaf(hv.y, w[4 * k + 1], ac1);
                    ac2 = fmaf(hv.z, w[4 * k + 2], ac2);
                    ac3 = fmaf(hv.w, w[4 * k + 3], ac3);
                }
                h0ring[s & 1][lane] = fast_tanh((ac0 + ac1) + (ac2 + ac3));
                a_pre = a_nxt;
                xv_n  = x_nxt;
            }
        } else if (wv == 1) {
            if (s >= 1 && s <= TLEN) {
                const float4* h4 = (const float4*)h0ring[(s + 1) & 1];
                float ac0 = 0.f, ac1 = 0.f, ac2 = 0.f, ac3 = 0.f;
                #pragma unroll
                for (int k = 0; k < 16; ++k) {
                    float4 hv = h4[k];
                    ac0 = fmaf(hv.x, w[4 * k + 0], ac0);
                    ac1 = fmaf(hv.y, w[4 * k + 1], ac1);
                    ac2 = fmaf(hv.z, w[4 * k + 2], ac2);
                    ac3 = fmaf(hv.w, w[4 * k + 3], ac3);
                }
                p1ring[(s + 1) & 1][lane] = (ac0 + ac1) + (ac2 + ac3);
            }
        } else {
            if (s >= 2) {
                float ac0 = p1ring[s & 1][lane] + b1s;
                float ac1 = 0.f, ac2 = 0.f, ac3 = 0.f;
                const float4* h4 = (const float4*)hs1;
                #pragma unroll
                for (int k = 0; k < 16; ++k) {
                    float4 hv = h4[k];
                    ac0 = fmaf(hv.x, w[4 * k + 0], ac0);
                    ac1 = fmaf(hv.y, w[4 * k + 1], ac1);
                    ac2 = fmaf(hv.z, w[4 * k + 2], ac2);
                    ac3 = fmaf(hv.w, w[4 * k + 3], ac3);
                }
                float h = fast_tanh((ac0 + ac1) + (ac2 + ac3));
                // single-wave RAW/WAR on hs1 is safe: same-wave DS ops are
                // ordered; all lanes' reads above precede this write
                hs1[lane] = h;
            }
        }
        __syncthreads();
    }

    // MLP head: y = relu(h1 @ W1^T + b1) @ W2^T + b2   (wave 0 only)
    if (wv == 0) {
        float r = 0.f;
        if (lane < 32) {
            float acc = b1[lane];
            const float* w1r = W1 + lane * HID;
            #pragma unroll
            for (int j = 0; j < HID; ++j) acc = fmaf(w1r[j], hs1[j], acc);
            r = fmaxf(acc, 0.f) * W2[lane];
        }
        #pragma unroll
        for (int off = 32; off > 0; off >>= 1) r += __shfl_down(r, off);
        if (lane == 0) out[b] = r + b2[0];
    }
}

extern "C" void kernel_launch(void* const* d_in, const int* in_sizes, int n_in,
                              void* d_out, int out_size, void* d_ws, size_t ws_size,
                              hipStream_t stream)
{
    const int*   x    = (const int*)d_in[0];
    const float* emb  = (const float*)d_in[1];
    const float* Wih0 = (const float*)d_in[2];
    const float* Whh0 = (const float*)d_in[3];
    const float* bih0 = (const float*)d_in[4];
    const float* bhh0 = (const float*)d_in[5];
    const float* Wih1 = (const float*)d_in[6];
    const float* Whh1 = (const float*)d_in[7];
    const float* bih1 = (const float*)d_in[8];
    const float* bhh1 = (const float*)d_in[9];
    const float* W1   = (const float*)d_in[10];
    const float* b1   = (const float*)d_in[11];
    const float* W2   = (const float*)d_in[12];
    const float* b2   = (const float*)d_in[13];

    float* P0 = (float*)d_ws;   // 512*64*4 = 128 KiB scratch

    hipLaunchKernelGGL(p0_kernel, dim3(VOCAB), dim3(HID), 0, stream,
                       emb, Wih0, bih0, bhh0, P0);
    hipLaunchKernelGGL(rnn_kernel, dim3(BATCH), dim3(192), 0, stream,
                       x, P0, Whh0, Wih1, Whh1, bih1, bhh1,
                       W1, b1, W2, b2, (float*)d_out);
}